// Round 2
// baseline (153.272 us; speedup 1.0000x reference)
//
#include <hip/hip_runtime.h>
#include <hip/hip_bf16.h>

typedef __hip_bfloat16 bf16;

#define NHEAD 8
#define SEQL  32
#define DKQ   8
static constexpr float W_MUL = 0.632455532033675866f;  // sqrt(2/5)
static constexpr float PI_F  = 3.14159265358979323846f;

// Workspace layout (floats): [0..63] flag, [64..319] Q, [320..575] K,
// [576..4671] V (2048 float2), [4672..6719] Z
#define WS_FLAG 0
#define WS_Q    64
#define WS_K    320
#define WS_V    576
#define WS_Z    4672

__device__ __forceinline__ float2 cmulf(float2 a, float2 b) {
    return make_float2(a.x*b.x - a.y*b.y, a.x*b.y + a.y*b.x);
}
__device__ __forceinline__ float2 caddf(float2 a, float2 b) {
    return make_float2(a.x + b.x, a.y + b.y);
}
// dtype-flag-selected load: storage is fp32 if f32, else bf16
__device__ __forceinline__ float ldf(const void* p, int i, bool f32) {
    return f32 ? ((const float*)p)[i]
               : __bfloat162float(((const bf16*)p)[i]);
}
// Inverse of the 6-qubit CNOT-ring permutation (bit5 = MSB = qubit0).
__device__ __forceinline__ int pinv6(int y) {
    int x5=(y>>5)&1, x4=(y>>4)&1, x3=(y>>3)&1, x2=(y>>2)&1, x1=(y>>1)&1, x0=y&1;
    x5^=x0; x0^=x1; x1^=x2; x2^=x3; x3^=x4; x4^=x5;
    return (x5<<5)|(x4<<4)|(x3<<3)|(x2<<2)|(x1<<1)|x0;
}

// ---------------------------------------------------------------------------
// Detect input storage dtype. Read x (2048 logical elems) as bf16 halves
// (4096 B, in-bounds under both hypotheses). bf16 N(0,1) data: ~0 anomalous
// exponents. fp32 storage: even halves are mantissa fragments/zeros -> >=500.
// flag = 1.0 if fp32 storage, else 0.0.
// ---------------------------------------------------------------------------
__global__ __launch_bounds__(64) void kDetect(const void* __restrict__ x,
                                              float* __restrict__ flag) {
    const unsigned short* u = (const unsigned short*)x;
    int t = threadIdx.x, cnt = 0;
    for (int i = t; i < 2048; i += 64) {
        int e = (u[i] >> 7) & 0xFF;
        if (e == 0xFF || e > 147 || e < 107) cnt++;   // inf/nan, >2^20, <2^-20 (incl 0)
    }
    cnt += __shfl_xor(cnt, 1, 64);
    cnt += __shfl_xor(cnt, 2, 64);
    cnt += __shfl_xor(cnt, 4, 64);
    cnt += __shfl_xor(cnt, 8, 64);
    cnt += __shfl_xor(cnt, 16, 64);
    cnt += __shfl_xor(cnt, 32, 64);
    if (t == 0) flag[WS_FLAG] = (cnt > 200) ? 1.0f : 0.0f;
}

// ---------------------------------------------------------------------------
// Kernel A: per (h,g) block (24 blocks x 64 threads).
//   g==0: Q[h,s] = sum_a sA(a)|phi_a|^2   (A = UC6^T MZ6 UC6 is diagonal,
//   g==1: K[h,s] = sum_b sB(b)|phi_b|^2    sign factorizes: parity(x5^x3^x1))
//   g==2: V[h,s][0..7] = phi = U8 psi_s   (vs is rank-1 = phi phi†)
// ---------------------------------------------------------------------------
__global__ __launch_bounds__(64) void kA(const void* __restrict__ x,
                                         const void* __restrict__ pqc_w,
                                         const void* __restrict__ W1,
                                         const void* __restrict__ b1,
                                         float* __restrict__ ws) {
    __shared__ float xq[SEQL][DKQ];
    __shared__ float psi[SEQL][DKQ];
    __shared__ float2 U8[64];

    float* Q  = ws + WS_Q;
    float* K  = ws + WS_K;
    float2* V = (float2*)(ws + WS_V);
    const bool f32 = ws[WS_FLAG] > 0.5f;

    const int t = threadIdx.x;
    const int h = blockIdx.x / 3, g = blockIdx.x % 3;

    // xq = x @ W1^T + b1
    for (int idx = t; idx < SEQL*DKQ; idx += 64) {
        int s = idx >> 3, k = idx & 7;
        float acc = ldf(b1, k, f32);
        for (int d = 0; d < 64; ++d)
            acc += ldf(x, s*64 + d, f32) * ldf(W1, k*64 + d, f32);
        xq[s][k] = acc;
    }
    __syncthreads();
    // psi = row-normalize(xq)
    for (int idx = t; idx < SEQL*DKQ; idx += 64) {
        int s = idx >> 3, k = idx & 7;
        float ss = 0.f;
        #pragma unroll
        for (int kk = 0; kk < 8; ++kk) ss += xq[s][kk]*xq[s][kk];
        psi[s][k] = xq[s][k] * rsqrtf(ss);
    }

    // u_q = rz(t2) @ ry(t1) @ rx(t0), redundant per thread
    float2 u[3][2][2];
    #pragma unroll
    for (int q = 0; q < 3; ++q) {
        int base = h*27 + g*9 + q*3;
        float t0 = ldf(pqc_w, base+0, f32) * W_MUL;
        float t1 = ldf(pqc_w, base+1, f32) * W_MUL;
        float t2 = ldf(pqc_w, base+2, f32) * W_MUL;
        float c0 = cosf(t0*0.5f), s0 = sinf(t0*0.5f);
        float c1 = cosf(t1*0.5f), s1 = sinf(t1*0.5f);
        float cz = cosf(t2*0.5f), sz = sinf(t2*0.5f);
        float2 m00 = make_float2(c1*c0,  s1*s0);
        float2 m01 = make_float2(-s1*c0, -c1*s0);
        float2 m10 = make_float2(s1*c0,  -c1*s0);
        float2 m11 = make_float2(c1*c0,  -s1*s0);
        float2 em = make_float2(cz, -sz), ep = make_float2(cz, sz);
        u[q][0][0] = cmulf(em, m00);  u[q][0][1] = cmulf(em, m01);
        u[q][1][0] = cmulf(ep, m10);  u[q][1][1] = cmulf(ep, m11);
    }
    {   // U8 = u0 ⊗ u1 ⊗ u2  (qubit0 = MSB)
        int r = t >> 3, c = t & 7;
        U8[t] = cmulf(cmulf(u[0][r>>2][c>>2], u[1][(r>>1)&1][(c>>1)&1]),
                      u[2][r&1][c&1]);
    }
    __syncthreads();

    // phi = U8 @ psi_s, 8 s at a time; lane = (sg<<3)|a
    const int sg = t >> 3, a = t & 7;
    for (int rnd = 0; rnd < 4; ++rnd) {
        int s = rnd*8 + sg;
        float2 phi = make_float2(0.f, 0.f);
        #pragma unroll
        for (int b = 0; b < 8; ++b) {
            float pb = psi[s][b];
            float2 ue = U8[a*8 + b];
            phi.x += ue.x * pb;
            phi.y += ue.y * pb;
        }
        if (g == 2) {
            V[(h*SEQL + s)*8 + a] = phi;
        } else {
            float mag = phi.x*phi.x + phi.y*phi.y;
            float sign = (g == 0) ? ((((a>>2) ^ a) & 1) ? -1.f : 1.f)   // sA: a2^a0
                                  : (((a>>1) & 1) ? -1.f : 1.f);        // sB: b1
            float val = sign * mag;
            val += __shfl_xor(val, 1, 64);
            val += __shfl_xor(val, 2, 64);
            val += __shfl_xor(val, 4, 64);
            if (a == 0) {
                if (g == 0) Q[h*SEQL + s] = val;
                else        K[h*SEQL + s] = val;
            }
        }
    }
}

// ---------------------------------------------------------------------------
// Kernel B: one wave per (h,i); 256 blocks x 64 threads.
// Lane l holds rho[a][c]. Sequential chain over j: w = (u1⊗u1⊗u1) phi_v(j),
// then rho <- partial-trace contraction (8 cross-lane FMAs, indices hoisted).
// ---------------------------------------------------------------------------
__global__ __launch_bounds__(64) void kB(const float* __restrict__ ws,
                                         float* __restrict__ Z) {
    const float* Q  = ws + WS_Q;
    const float* Kv = ws + WS_K;
    const float2* V = (const float2*)(ws + WS_V);

    const int l = threadIdx.x;
    const int h = blockIdx.x >> 5, i = blockIdx.x & 31;
    const int a = l >> 3, c = l & 7;

    int srcLane[8], bx[8], by[8];
    #pragma unroll
    for (int b = 0; b < 8; ++b) {
        int ia = pinv6(a*8 + b);
        int ic = pinv6(c*8 + b);
        srcLane[b] = ((ia >> 3) << 3) | (ic >> 3);
        bx[b] = ia & 7;
        by[b] = ic & 7;
    }

    const float qhi = Q[h*SEQL + i];
    float rr = 0.f, ri = 0.f;

    for (int j = 0; j < SEQL; ++j) {
        float phi = PI_F * qhi * Kv[h*SEQL + j];
        // u1 = rz(phi) @ ry(phi/2) @ rx(phi/2)
        float c1 = cosf(phi*0.25f), s1 = sinf(phi*0.25f);
        float ch = cosf(phi*0.5f),  sh = sinf(phi*0.5f);
        float2 em = make_float2(ch, -sh), ep = make_float2(ch, sh);
        float sc = s1*c1;
        float2 u00 = cmulf(em, make_float2(c1*c1,  s1*s1));
        float2 u01 = cmulf(em, make_float2(-sc, -sc));
        float2 u10 = cmulf(ep, make_float2(sc, -sc));
        float2 u11 = cmulf(ep, make_float2(c1*c1, -s1*s1));

        // w = (u1 ⊗ u1 ⊗ u1) v_j
        float2 w[8];
        #pragma unroll
        for (int b = 0; b < 8; ++b) w[b] = V[(h*SEQL + j)*8 + b];
        #pragma unroll
        for (int p = 0; p < 4; ++p) {            // qubit 0 (MSB), stride 4
            float2 lo = w[p], hi = w[p+4];
            w[p]   = caddf(cmulf(u00, lo), cmulf(u01, hi));
            w[p+4] = caddf(cmulf(u10, lo), cmulf(u11, hi));
        }
        #pragma unroll
        for (int p = 0; p < 4; ++p) {            // qubit 1, stride 2
            int i0 = ((p >> 1) << 2) | (p & 1);  // 0,1,4,5
            float2 lo = w[i0], hi = w[i0+2];
            w[i0]   = caddf(cmulf(u00, lo), cmulf(u01, hi));
            w[i0+2] = caddf(cmulf(u10, lo), cmulf(u11, hi));
        }
        #pragma unroll
        for (int p = 0; p < 4; ++p) {            // qubit 2 (LSB), stride 1
            float2 lo = w[2*p], hi = w[2*p+1];
            w[2*p]   = caddf(cmulf(u00, lo), cmulf(u01, hi));
            w[2*p+1] = caddf(cmulf(u10, lo), cmulf(u11, hi));
        }

        if (j == 0) {
            rr = w[a].x*w[c].x + w[a].y*w[c].y;
            ri = w[a].y*w[c].x - w[a].x*w[c].y;
        } else {
            float nr = 0.f, ni = 0.f;
            #pragma unroll
            for (int b = 0; b < 8; ++b) {
                float pr = __shfl(rr, srcLane[b], 64);
                float pi = __shfl(ri, srcLane[b], 64);
                float2 wx = w[bx[b]], wy = w[by[b]];
                float sr = wx.x*wy.x + wx.y*wy.y;   // w[bx] * conj(w[by])
                float si = wx.y*wy.x - wx.x*wy.y;
                nr += pr*sr - pi*si;
                ni += pr*si + pi*sr;
            }
            rr = nr; ri = ni;
        }
    }
    if (a == c) Z[(h*SEQL + i)*8 + a] = rr;
}

// ---------------------------------------------------------------------------
// Kernel C: out[s,m] = b2[m] + sum_c zs[s,c] * W2[m,c]; output dtype matches
// detected input dtype.
// ---------------------------------------------------------------------------
__global__ __launch_bounds__(64) void kC(const float* __restrict__ ws,
                                         const void* __restrict__ W2,
                                         const void* __restrict__ b2,
                                         void* __restrict__ out) {
    const float* Z = ws + WS_Z;
    const bool f32 = ws[WS_FLAG] > 0.5f;
    const int s = blockIdx.x, m = threadIdx.x;
    float acc = ldf(b2, m, f32);
    #pragma unroll
    for (int cc = 0; cc < 64; ++cc) {
        float z = Z[(cc >> 3)*256 + s*8 + (cc & 7)];
        acc += z * ldf(W2, m*64 + cc, f32);
    }
    if (f32) ((float*)out)[s*64 + m] = acc;
    else     ((bf16*)out)[s*64 + m] = __float2bfloat16(acc);
}

extern "C" void kernel_launch(void* const* d_in, const int* in_sizes, int n_in,
                              void* d_out, int out_size, void* d_ws, size_t ws_size,
                              hipStream_t stream) {
    const void* x     = d_in[0];
    const void* pqc_w = d_in[1];
    const void* W1    = d_in[2];
    const void* b1    = d_in[3];
    const void* W2    = d_in[4];
    const void* b2    = d_in[5];
    // d_in[6] = edge_index (unused)

    float* ws = (float*)d_ws;

    hipLaunchKernelGGL(kDetect, dim3(1),  dim3(64), 0, stream, x, ws);
    hipLaunchKernelGGL(kA,      dim3(24), dim3(64), 0, stream, x, pqc_w, W1, b1, ws);
    hipLaunchKernelGGL(kB,      dim3(256),dim3(64), 0, stream, ws, ws + WS_Z);
    hipLaunchKernelGGL(kC,      dim3(32), dim3(64), 0, stream, ws, W2, b2, d_out);
}

// Round 3
// 76.862 us; speedup vs baseline: 1.9941x; 1.9941x over previous
//
#include <hip/hip_runtime.h>
#include <hip/hip_bf16.h>

#define NHEAD 8
#define SEQL  32
#define DKQ   8
static constexpr float W_MUL = 0.632455532033675866f;  // sqrt(2/5)
static constexpr float PI_F  = 3.14159265358979323846f;

// Workspace layout (floats): inputs are fp32 (verified: round-1 bf16 read -> NaN,
// round-2 runtime detection chose fp32 and passed; reference declares float32).
#define WS_Q 0
#define WS_K 256
#define WS_V 512
#define WS_Z 4608

__device__ __forceinline__ float2 cmulf(float2 a, float2 b) {
    return make_float2(a.x*b.x - a.y*b.y, a.x*b.y + a.y*b.x);
}
__device__ __forceinline__ float2 caddf(float2 a, float2 b) {
    return make_float2(a.x + b.x, a.y + b.y);
}
// sigma(a) = (a2, a1^a2, a0^a1): the hi-part linear map of pinv6 (CNOT-ring inverse)
__device__ __forceinline__ int sig3(int a) {
    int a2=(a>>2)&1, a1=(a>>1)&1, a0=a&1;
    return (a2<<2) | ((a1^a2)<<1) | (a0^a1);
}

// ---------------------------------------------------------------------------
// k1: per (h,g) block (24 blocks x 256 threads).
//   g==0: Q[h,s] = sum_a sA(a)|phi_a|^2   (A = UC6^T MZ6 UC6 is diagonal)
//   g==1: K[h,s] = sum_b sB(b)|phi_b|^2
//   g==2: V[h,s][0..7] = phi = U8 psi_s   (vs is rank-1 = phi phi†)
// ---------------------------------------------------------------------------
__global__ __launch_bounds__(256) void k1(const float* __restrict__ x,
                                          const float* __restrict__ pqc_w,
                                          const float* __restrict__ W1,
                                          const float* __restrict__ b1,
                                          float* __restrict__ ws) {
    __shared__ float xq[SEQL][DKQ];
    __shared__ float psi[SEQL][DKQ];
    __shared__ float2 U8[64];

    float* Q  = ws + WS_Q;
    float* K  = ws + WS_K;
    float2* V = (float2*)(ws + WS_V);

    const int t = threadIdx.x;
    const int h = blockIdx.x / 3, g = blockIdx.x % 3;

    // xq[s][k] = x[s]·W1[k] + b1[k]; one dot per thread, float4 loads
    {
        const int s = t >> 3, k = t & 7;
        const float4* xr = (const float4*)(x  + s*64);
        const float4* wr = (const float4*)(W1 + k*64);
        float acc = b1[k];
        #pragma unroll
        for (int q = 0; q < 16; ++q) {
            float4 xa = xr[q], wa = wr[q];
            acc += xa.x*wa.x + xa.y*wa.y + xa.z*wa.z + xa.w*wa.w;
        }
        xq[s][k] = acc;
    }
    __syncthreads();
    {
        const int s = t >> 3, k = t & 7;
        float ss = 0.f;
        #pragma unroll
        for (int kk = 0; kk < 8; ++kk) ss += xq[s][kk]*xq[s][kk];
        psi[s][k] = xq[s][k] * rsqrtf(ss);
    }

    // U8 = u0 ⊗ u1 ⊗ u2 built by first wave
    if (t < 64) {
        float2 u[3][2][2];
        #pragma unroll
        for (int q = 0; q < 3; ++q) {
            int base = h*27 + g*9 + q*3;
            float t0 = pqc_w[base+0] * W_MUL;
            float t1 = pqc_w[base+1] * W_MUL;
            float t2 = pqc_w[base+2] * W_MUL;
            float c0 = cosf(t0*0.5f), s0 = sinf(t0*0.5f);
            float c1 = cosf(t1*0.5f), s1 = sinf(t1*0.5f);
            float cz = cosf(t2*0.5f), sz = sinf(t2*0.5f);
            float2 m00 = make_float2(c1*c0,  s1*s0);
            float2 m01 = make_float2(-s1*c0, -c1*s0);
            float2 m10 = make_float2(s1*c0,  -c1*s0);
            float2 m11 = make_float2(c1*c0,  -s1*s0);
            float2 em = make_float2(cz, -sz), ep = make_float2(cz, sz);
            u[q][0][0] = cmulf(em, m00);  u[q][0][1] = cmulf(em, m01);
            u[q][1][0] = cmulf(ep, m10);  u[q][1][1] = cmulf(ep, m11);
        }
        int r = t >> 3, c = t & 7;
        U8[t] = cmulf(cmulf(u[0][r>>2][c>>2], u[1][(r>>1)&1][(c>>1)&1]),
                      u[2][r&1][c&1]);
    }
    __syncthreads();

    // phi = U8 @ psi_s; wave w handles s = w*8 + (lane>>3), a = lane&7
    {
        const int lane = t & 63, wv = t >> 6;
        const int sg = lane >> 3, a = lane & 7;
        const int s = wv*8 + sg;
        float2 phi = make_float2(0.f, 0.f);
        #pragma unroll
        for (int b = 0; b < 8; ++b) {
            float pb = psi[s][b];
            float2 ue = U8[a*8 + b];
            phi.x += ue.x * pb;
            phi.y += ue.y * pb;
        }
        if (g == 2) {
            V[(h*SEQL + s)*8 + a] = phi;
        } else {
            float mag = phi.x*phi.x + phi.y*phi.y;
            float sign = (g == 0) ? ((((a>>2) ^ a) & 1) ? -1.f : 1.f)   // sA: a2^a0
                                  : (((a>>1) & 1) ? -1.f : 1.f);        // sB: b1
            float val = sign * mag;
            val += __shfl_xor(val, 1, 64);
            val += __shfl_xor(val, 2, 64);
            val += __shfl_xor(val, 4, 64);
            if (a == 0) {
                if (g == 0) Q[h*SEQL + s] = val;
                else        K[h*SEQL + s] = val;
            }
        }
    }
}

// ---------------------------------------------------------------------------
// k2: one wave per (h,i); 256 blocks x 64 threads.
// Phase 1 (parallel over j): build w_j = (u1⊗u1⊗u1)V[h,j], reduce to 8 complex
// coefficients C_p(a0,c0) = sum_{par(m)=p} w[4a0^m] conj(w[4c0^m]); store in LDS.
// Phase 2 (serial over j): rho'[a][c] = C0·rho[σ(a)][σ(c)] + C1·rho[σ(a)^6][σ(c)^6]
//   -> 1 ds_read_b128 + 4 bpermutes (fixed permutations, conflict-free) + 8 FMA.
// ---------------------------------------------------------------------------
__global__ __launch_bounds__(64) void k2(const float* __restrict__ ws,
                                         float* __restrict__ Z) {
    __shared__ __align__(16) float2 Carr[SEQL][4][2];  // [j][a0*2+c0][parity]
    __shared__ float2 w0s[8];

    const float*  Q  = ws + WS_Q;
    const float*  Kv = ws + WS_K;
    const float2* V  = (const float2*)(ws + WS_V);

    const int l = threadIdx.x;
    const int h = blockIdx.x >> 5, i = blockIdx.x & 31;
    const float qhi = Q[h*SEQL + i];

    // ---- phase 1: j = l&31, half = l>>5 ----
    {
        const int j = l & 31, half = l >> 5;
        float phi = PI_F * qhi * Kv[h*SEQL + j];
        float c1 = cosf(phi*0.25f), s1 = sinf(phi*0.25f);
        float ch = cosf(phi*0.5f),  sh = sinf(phi*0.5f);
        float2 em = make_float2(ch, -sh), ep = make_float2(ch, sh);
        float sc = s1*c1;
        float2 u00 = cmulf(em, make_float2(c1*c1,  s1*s1));
        float2 u01 = cmulf(em, make_float2(-sc, -sc));
        float2 u10 = cmulf(ep, make_float2(sc, -sc));
        float2 u11 = cmulf(ep, make_float2(c1*c1, -s1*s1));

        float2 w[8];
        #pragma unroll
        for (int b = 0; b < 8; ++b) w[b] = V[(h*SEQL + j)*8 + b];
        #pragma unroll
        for (int p = 0; p < 4; ++p) {            // qubit 0 (MSB), stride 4
            float2 lo = w[p], hi = w[p+4];
            w[p]   = caddf(cmulf(u00, lo), cmulf(u01, hi));
            w[p+4] = caddf(cmulf(u10, lo), cmulf(u11, hi));
        }
        #pragma unroll
        for (int p = 0; p < 4; ++p) {            // qubit 1, stride 2
            int i0 = ((p >> 1) << 2) | (p & 1);  // 0,1,4,5
            float2 lo = w[i0], hi = w[i0+2];
            w[i0]   = caddf(cmulf(u00, lo), cmulf(u01, hi));
            w[i0+2] = caddf(cmulf(u10, lo), cmulf(u11, hi));
        }
        #pragma unroll
        for (int p = 0; p < 4; ++p) {            // qubit 2 (LSB), stride 1
            float2 lo = w[2*p], hi = w[2*p+1];
            w[2*p]   = caddf(cmulf(u00, lo), cmulf(u01, hi));
            w[2*p+1] = caddf(cmulf(u10, lo), cmulf(u11, hi));
        }

        if (j == 0 && half == 0) {
            #pragma unroll
            for (int b = 0; b < 8; ++b) w0s[b] = w[b];
        }
        // C_{half}(a0,c0): m-sets by parity
        const int mset0[4] = {0,3,5,6}, mset1[4] = {1,2,4,7};
        #pragma unroll
        for (int combo = 0; combo < 4; ++combo) {
            int a0 = combo >> 1, c0 = combo & 1;
            float2 acc = make_float2(0.f, 0.f);
            #pragma unroll
            for (int tt = 0; tt < 4; ++tt) {
                int m = half ? mset1[tt] : mset0[tt];
                float2 wx = w[(a0<<2)^m], wy = w[(c0<<2)^m];
                acc.x += wx.x*wy.x + wx.y*wy.y;   // w[x]·conj(w[y])
                acc.y += wx.y*wy.x - wx.x*wy.y;
            }
            Carr[j][combo][half] = acc;
        }
    }
    __syncthreads();

    // ---- phase 2: serial chain ----
    const int a = l >> 3, c = l & 7;
    const int combo = ((a & 1) << 1) | (c & 1);
    const int src0 = (sig3(a) << 3) | sig3(c);
    const int src1 = src0 ^ 54;                   // ^ (6<<3 | 6)

    float2 wa = w0s[a], wc = w0s[c];
    float rr = wa.x*wc.x + wa.y*wc.y;             // rho = w0 w0†
    float ri = wa.y*wc.x - wa.x*wc.y;

    for (int j = 1; j < SEQL; ++j) {
        float4 Cv = *((const float4*)&Carr[j][combo][0]);  // (C0.re,C0.im,C1.re,C1.im)
        float R0r = __shfl(rr, src0, 64);
        float R0i = __shfl(ri, src0, 64);
        float R1r = __shfl(rr, src1, 64);
        float R1i = __shfl(ri, src1, 64);
        float nr = Cv.x*R0r - Cv.y*R0i + Cv.z*R1r - Cv.w*R1i;
        float ni = Cv.x*R0i + Cv.y*R0r + Cv.z*R1i + Cv.w*R1r;
        rr = nr; ri = ni;
    }
    if (a == c) Z[(h*SEQL + i)*8 + a] = rr;
}

// ---------------------------------------------------------------------------
// k3: out[s,m] = b2[m] + sum_c zs[s,c] * W2[m,c]; 32 blocks x 64 threads.
// ---------------------------------------------------------------------------
__global__ __launch_bounds__(64) void k3(const float* __restrict__ ws,
                                         const float* __restrict__ W2,
                                         const float* __restrict__ b2,
                                         float* __restrict__ out) {
    const float* Z = ws + WS_Z;
    const int s = blockIdx.x, m = threadIdx.x;
    float acc = b2[m];
    #pragma unroll
    for (int cc = 0; cc < 64; ++cc) {
        float z = Z[(cc >> 3)*256 + s*8 + (cc & 7)];
        acc += z * W2[m*64 + cc];
    }
    out[s*64 + m] = acc;
}

extern "C" void kernel_launch(void* const* d_in, const int* in_sizes, int n_in,
                              void* d_out, int out_size, void* d_ws, size_t ws_size,
                              hipStream_t stream) {
    const float* x     = (const float*)d_in[0];
    const float* pqc_w = (const float*)d_in[1];
    const float* W1    = (const float*)d_in[2];
    const float* b1    = (const float*)d_in[3];
    const float* W2    = (const float*)d_in[4];
    const float* b2    = (const float*)d_in[5];
    // d_in[6] = edge_index (unused)

    float* ws = (float*)d_ws;

    hipLaunchKernelGGL(k1, dim3(24),  dim3(256), 0, stream, x, pqc_w, W1, b1, ws);
    hipLaunchKernelGGL(k2, dim3(256), dim3(64),  0, stream, ws, ws + WS_Z);
    hipLaunchKernelGGL(k3, dim3(32),  dim3(64),  0, stream, ws, W2, b2, (float*)d_out);
}